// Round 1
// baseline (378.329 us; speedup 1.0000x reference)
//
#include <hip/hip_runtime.h>

// NestedMoEModel: B=32768, D=256, H=256, G=8, E=8.
// softmax row-sum == 1 => gate branch drops; sum_e is linear =>
// single GEMM  out[32768,2048] = x @ (sum_e W_exp)^T + sum_e b_exp.
// R3: fuse x fp32->bf16 conversion INTO the GEMM A-staging (kills the xb
// HBM round-trip + the serialized 2048-block conversion pass), prep only
// folds W_exp. XCD-chunked block swizzle so the 16 n-blocks sharing an
// A-panel land on one XCD's L2.

typedef unsigned short u16;
typedef __bf16 bf16x8 __attribute__((ext_vector_type(8)));
typedef float f32x4 __attribute__((ext_vector_type(4)));

#define MB 32768   // batch (GEMM M)
#define NN 2048    // G*H   (GEMM N)
#define KK 256     // D     (GEMM K)
#define BK 64

__device__ __forceinline__ u16 f2bf(float f) {
    unsigned u = __builtin_bit_cast(unsigned, f);
    u += 0x7FFFu + ((u >> 16) & 1u);
    return (u16)(u >> 16);
}

// packed fp32x2 -> bf16x2 (RNE), no builtin on gfx950 — inline asm (learn_hip m240)
__device__ __forceinline__ unsigned cvtpk(float lo, float hi) {
    unsigned r;
    asm("v_cvt_pk_bf16_f32 %0, %1, %2" : "=v"(r) : "v"(lo), "v"(hi));
    return r;
}

__device__ __forceinline__ void gld16(const void* g, void* l) {
    // async global->LDS, 16B/lane; LDS dest must be wave-uniform base + lane*16
    __builtin_amdgcn_global_load_lds((const __attribute__((address_space(1))) void*)g,
                                     (__attribute__((address_space(3))) void*)l,
                                     16, 0, 0);
}

// ---------------- prep: Wsum (bf16) + bsum fold only ----------------
__global__ __launch_bounds__(256) void prep_kernel(
    const float* __restrict__ Wexp, const float* __restrict__ bexp,
    u16* __restrict__ Ws, float* __restrict__ bs)
{
    const int tid = blockIdx.x * 256 + threadIdx.x;  // 0..131071
    const int n = tid >> 6;                          // 0..2047
    const int i = (tid & 63) << 2;                   // 0..252
    const int g = n >> 8, h = n & 255;
    const float* base = Wexp + ((size_t)(g * 8) * 256 + h) * 256 + i;
    float s0 = 0.f, s1 = 0.f, s2 = 0.f, s3 = 0.f;
#pragma unroll
    for (int e = 0; e < 8; ++e) {
        const float4 v = *(const float4*)(base + (size_t)e * 65536);
        s0 += v.x; s1 += v.y; s2 += v.z; s3 += v.w;
    }
    ushort4 o;
    o.x = f2bf(s0); o.y = f2bf(s1); o.z = f2bf(s2); o.w = f2bf(s3);
    *(ushort4*)(Ws + (size_t)n * KK + i) = o;
    if ((tid & 63) == 0) {
        float sb = 0.f;
#pragma unroll
        for (int e = 0; e < 8; ++e) sb += bexp[(g * 8 + e) * 256 + h];
        bs[n] = sb;
    }
}

// ---------------- GEMM: C = x * Ws^T + bias, fused fp32->bf16 on A ----------------
// 128x128 tile, BK=64, 4 waves (2x2 of 64x64), 16x16x32 bf16 MFMA.
// LDS layout: row-major 128 x 64 bf16, each row's eight 8-elem chunks permuted
// by chunk^(row&7) (conflict-free ds_read_b128 / ds_write_b128).
// A: reg-staged (float4 loads -> v_cvt_pk_bf16_f32 -> swizzled ds_write_b128).
// B: async global_load_lds with the swizzle pre-applied on the GLOBAL source
//    address (glds LDS dest is forced to base+lane*16).
__global__ __launch_bounds__(256, 3) void gemm_kernel(
    const float* __restrict__ X, const u16* __restrict__ Bt,
    const float* __restrict__ bias, float* __restrict__ C)
{
    __shared__ __align__(16) u16 sA[128 * BK];
    __shared__ __align__(16) u16 sB[128 * BK];

    const int t = threadIdx.x;

    // XCD-chunked swizzle: 4096 blocks, 8 XCDs, 512/XCD (bijective: 4096%8==0).
    // Logical id n-fastest so the 16 blocks sharing an A-panel are consecutive
    // (same XCD, same L2).
    const int bid  = blockIdx.x;
    const int rmap = (bid & 7) * 512 + (bid >> 3);
    const int n0 = (rmap & 15) << 7;
    const int m0 = (rmap >> 4) << 7;

    const int lane = t & 63;
    const int w = t >> 6;
    const int wm = (w & 1) << 6;
    const int wn = (w >> 1) << 6;
    const int lr = lane & 15;
    const int quad = lane >> 4;

    f32x4 acc[4][4] = {};

    // staging decomposition: slot = r*256+t -> row = slot>>3, chunk = slot&7
    const int srow = t >> 3;
    const int scs  = t & 7;

    for (int k0 = 0; k0 < KK; k0 += BK) {
        // B first: async engine starts while we pull A through registers
#pragma unroll
        for (int r = 0; r < 4; ++r) {
            const int row = srow + r * 32;
            const int gc  = ((scs ^ (row & 7)) << 3);   // swizzled element offset
            gld16(Bt + (size_t)(n0 + row) * KK + k0 + gc, sB + (size_t)(r * 256 + t) * 8);
        }
        // A: batch all 8 float4 loads (MLP), then convert+write
        f32x4 va[8];
#pragma unroll
        for (int r = 0; r < 4; ++r) {
            const float* src = X + (size_t)(m0 + srow + r * 32) * KK + k0 + (scs << 3);
            va[2 * r]     = *(const f32x4*)(src);
            va[2 * r + 1] = *(const f32x4*)(src + 4);
        }
#pragma unroll
        for (int r = 0; r < 4; ++r) {
            const int row = srow + r * 32;
            const int sc  = (scs ^ (row & 7)) << 3;     // swizzle on LDS write side
            uint4 pk;
            pk.x = cvtpk(va[2 * r][0], va[2 * r][1]);
            pk.y = cvtpk(va[2 * r][2], va[2 * r][3]);
            pk.z = cvtpk(va[2 * r + 1][0], va[2 * r + 1][1]);
            pk.w = cvtpk(va[2 * r + 1][2], va[2 * r + 1][3]);
            *(uint4*)(sA + row * BK + sc) = pk;
        }
        __syncthreads();

#pragma unroll
        for (int kk = 0; kk < 2; ++kk) {
            bf16x8 af[4], bf[4];
#pragma unroll
            for (int mi = 0; mi < 4; ++mi) {
                const int rr = wm + mi * 16 + lr;
                const int c  = (kk * 4 + quad) ^ (rr & 7);
                af[mi] = *(const bf16x8*)(sA + rr * BK + (c << 3));
            }
#pragma unroll
            for (int ni = 0; ni < 4; ++ni) {
                const int rr = wn + ni * 16 + lr;
                const int c  = (kk * 4 + quad) ^ (rr & 7);
                bf[ni] = *(const bf16x8*)(sB + rr * BK + (c << 3));
            }
#pragma unroll
            for (int mi = 0; mi < 4; ++mi)
#pragma unroll
                for (int ni = 0; ni < 4; ++ni)
                    acc[mi][ni] = __builtin_amdgcn_mfma_f32_16x16x32_bf16(
                        af[mi], bf[ni], acc[mi][ni], 0, 0, 0);
        }
        __syncthreads();
    }

    // epilogue: C/D layout col=lane&15, row=quad*4+reg (m89-verified)
#pragma unroll
    for (int ni = 0; ni < 4; ++ni) {
        const int col = n0 + wn + ni * 16 + lr;
        const float bv = bias[col];
#pragma unroll
        for (int mi = 0; mi < 4; ++mi) {
            const int row = m0 + wm + mi * 16 + quad * 4;
            float* Cp = C + (size_t)row * NN + col;
#pragma unroll
            for (int r = 0; r < 4; ++r)
                Cp[(size_t)r * NN] = acc[mi][ni][r] + bv;
        }
    }
}

extern "C" void kernel_launch(void* const* d_in, const int* in_sizes, int n_in,
                              void* d_out, int out_size, void* d_ws, size_t ws_size,
                              hipStream_t stream) {
    const float* x    = (const float*)d_in[0];
    // d_in[1] = W_gate, d_in[2] = b_gate: unused (softmax row-sum == 1)
    const float* Wexp = (const float*)d_in[3];
    const float* bexp = (const float*)d_in[4];
    float* out = (float*)d_out;

    u16*   Ws = (u16*)d_ws;                            // 1 MB
    float* bs = (float*)((char*)d_ws + 1048576);       // 8 KB

    prep_kernel<<<512, 256, 0, stream>>>(Wexp, bexp, Ws, bs);
    dim3 grid(4096);
    gemm_kernel<<<grid, 256, 0, stream>>>(x, Ws, bs, out);
}

// Round 2
// 341.314 us; speedup vs baseline: 1.1084x; 1.1084x over previous
//
#include <hip/hip_runtime.h>

// NestedMoEModel: B=32768, D=256, H=256, G=8, E=8.
// softmax row-sum == 1 => gate branch drops; sum_e is linear =>
// single GEMM  out[32768,2048] = x @ (sum_e W_exp)^T + sum_e b_exp.
// R4: back to R0's proven prep(xb,Ws,bs) + glds GEMM (R1's reg-staged A
// regressed per m151). New: (1) 2-phase double-buffered K-loop with COUNTED
// s_waitcnt vmcnt(8) + raw s_barrier (loads stay in flight across barriers),
// (2) swapped-operand MFMA so acc reg-index runs along n -> float4 C stores.

typedef unsigned short u16;
typedef __bf16 bf16x8 __attribute__((ext_vector_type(8)));
typedef float f32x4 __attribute__((ext_vector_type(4)));

#define MB 32768   // batch (GEMM M)
#define NN 2048    // G*H   (GEMM N)
#define KK 256     // D     (GEMM K)
#define BK 64

__device__ __forceinline__ u16 f2bf(float f) {
    unsigned u = __builtin_bit_cast(unsigned, f);
    u += 0x7FFFu + ((u >> 16) & 1u);
    return (u16)(u >> 16);
}

__device__ __forceinline__ void gld16(const void* g, void* l) {
    // async global->LDS, 16B/lane; LDS dest must be wave-uniform base + lane*16
    __builtin_amdgcn_global_load_lds((const __attribute__((address_space(1))) void*)g,
                                     (__attribute__((address_space(3))) void*)l,
                                     16, 0, 0);
}

// ---------------- prep: Wsum/bsum fold + x fp32->bf16 (R0-proven) ----------------
__global__ __launch_bounds__(256) void prep_kernel(
    const float* __restrict__ x, const float* __restrict__ Wexp,
    const float* __restrict__ bexp, u16* __restrict__ xb,
    u16* __restrict__ Ws, float* __restrict__ bs)
{
    const int blk = blockIdx.x;
    const int t = threadIdx.x;
    if (blk < 512) {
        const int tid = blk * 256 + t;        // 0..131071
        const int n = tid >> 6;               // 0..2047
        const int i = (tid & 63) << 2;        // 0..252
        const int g = n >> 8, h = n & 255;
        const float* base = Wexp + ((size_t)(g * 8) * 256 + h) * 256 + i;
        float s0 = 0.f, s1 = 0.f, s2 = 0.f, s3 = 0.f;
#pragma unroll
        for (int e = 0; e < 8; ++e) {
            const float4 v = *(const float4*)(base + (size_t)e * 65536);
            s0 += v.x; s1 += v.y; s2 += v.z; s3 += v.w;
        }
        ushort4 o;
        o.x = f2bf(s0); o.y = f2bf(s1); o.z = f2bf(s2); o.w = f2bf(s3);
        *(ushort4*)(Ws + (size_t)n * KK + i) = o;
        if ((tid & 63) == 0) {
            float sb = 0.f;
#pragma unroll
            for (int e = 0; e < 8; ++e) sb += bexp[(g * 8 + e) * 256 + h];
            bs[n] = sb;
        }
    } else {
        int idx = (blk - 512) * 256 + t;      // 0..524287
        const float4* xv = (const float4*)x;
#pragma unroll
        for (int it = 0; it < 4; ++it) {
            const int j = idx + it * 524288;
            const float4 v = xv[j];
            ushort4 o;
            o.x = f2bf(v.x); o.y = f2bf(v.y); o.z = f2bf(v.z); o.w = f2bf(v.w);
            *(ushort4*)(xb + (size_t)j * 4) = o;
        }
    }
}

// ---------------- GEMM: C = A * Bt^T + bias ----------------
// 128x128 tile, BK=64, 4 waves (2x2 of 64x64), 16x16x32 bf16 MFMA.
// LDS: double-buffered row-major 128x64 bf16 per operand (64 KB total,
// 2 blocks/CU); each row's eight 8-elem chunks permuted by chunk^(row&7),
// applied on the GLOBAL source address (glds dest forced to base+lane*16).
// K-loop: issue next tile's 16 glds, s_waitcnt vmcnt(8) (current tile done,
// next stays in flight), raw s_barrier, compute, barrier, flip.
__global__ __launch_bounds__(256, 2) void gemm_kernel(
    const u16* __restrict__ A, const u16* __restrict__ Bt,
    const float* __restrict__ bias, float* __restrict__ C)
{
    __shared__ __align__(16) u16 sA[2][128 * BK];
    __shared__ __align__(16) u16 sB[2][128 * BK];

    const int t = threadIdx.x;
    const int n0 = blockIdx.x * 128;   // x fastest: 16 consecutive blocks share A-tile
    const int m0 = blockIdx.y * 128;

    const int lane = t & 63;
    const int w = t >> 6;
    const int wm = (w & 1) << 6;
    const int wn = (w >> 1) << 6;
    const int lr = lane & 15;
    const int quad = lane >> 4;

    f32x4 acc[4][4] = {};

    // staging decomposition: slot = r*256+t -> row = slot>>3, chunk = slot&7
    const int srow = t >> 3;
    const int scs  = t & 7;

#define STAGE(P, K0)                                                              \
    {                                                                             \
        _Pragma("unroll")                                                         \
        for (int r = 0; r < 4; ++r) {                                             \
            const int row = srow + r * 32;                                        \
            const int gc  = ((scs ^ (row & 7)) << 3);                             \
            gld16(A  + (size_t)(m0 + row) * KK + (K0) + gc,                       \
                  sA[P] + (size_t)(r * 256 + t) * 8);                             \
            gld16(Bt + (size_t)(n0 + row) * KK + (K0) + gc,                       \
                  sB[P] + (size_t)(r * 256 + t) * 8);                             \
        }                                                                         \
    }

    STAGE(0, 0);
    int p = 0;
#pragma unroll
    for (int it = 0; it < 4; ++it) {
        if (it < 3) {
            STAGE(p ^ 1, (it + 1) * BK);
            asm volatile("s_waitcnt vmcnt(8)" ::: "memory");  // tile it landed; next in flight
        } else {
            asm volatile("s_waitcnt vmcnt(0)" ::: "memory");
        }
        __builtin_amdgcn_s_barrier();

#pragma unroll
        for (int kk = 0; kk < 2; ++kk) {
            bf16x8 af[4], bf[4];
#pragma unroll
            for (int mi = 0; mi < 4; ++mi) {
                const int rr = wm + mi * 16 + lr;
                const int c  = (kk * 4 + quad) ^ (rr & 7);
                af[mi] = *(const bf16x8*)(sA[p] + rr * BK + (c << 3));
            }
#pragma unroll
            for (int ni = 0; ni < 4; ++ni) {
                const int rr = wn + ni * 16 + lr;
                const int c  = (kk * 4 + quad) ^ (rr & 7);
                bf[ni] = *(const bf16x8*)(sB[p] + rr * BK + (c << 3));
            }
            // SWAPPED operands: D[row=quad*4+r <- n][col=lane&15 <- m]
            // => acc[mi][ni][r] = C[m0+wm+mi*16+lr][n0+wn+ni*16+quad*4+r]
#pragma unroll
            for (int mi = 0; mi < 4; ++mi)
#pragma unroll
                for (int ni = 0; ni < 4; ++ni)
                    acc[mi][ni] = __builtin_amdgcn_mfma_f32_16x16x32_bf16(
                        bf[ni], af[mi], acc[mi][ni], 0, 0, 0);
        }
        if (it < 3) __builtin_amdgcn_s_barrier();  // readers done before restage
        p ^= 1;
    }
#undef STAGE

    // epilogue: float4 stores along n (reg index r runs along n after swap)
#pragma unroll
    for (int mi = 0; mi < 4; ++mi) {
        const int row = m0 + wm + mi * 16 + lr;
        float* Cp = C + (size_t)row * NN;
#pragma unroll
        for (int ni = 0; ni < 4; ++ni) {
            const int col = n0 + wn + ni * 16 + quad * 4;
            const f32x4 bv = *(const f32x4*)(bias + col);
            f32x4 v = acc[mi][ni] + bv;
            *(f32x4*)(Cp + col) = v;
        }
    }
}

extern "C" void kernel_launch(void* const* d_in, const int* in_sizes, int n_in,
                              void* d_out, int out_size, void* d_ws, size_t ws_size,
                              hipStream_t stream) {
    const float* x    = (const float*)d_in[0];
    // d_in[1] = W_gate, d_in[2] = b_gate: unused (softmax row-sum == 1)
    const float* Wexp = (const float*)d_in[3];
    const float* bexp = (const float*)d_in[4];
    float* out = (float*)d_out;

    u16*   xb = (u16*)d_ws;                                         // 16 MB
    u16*   Ws = (u16*)((char*)d_ws + (size_t)16777216);             // 1 MB
    float* bs = (float*)((char*)d_ws + (size_t)16777216 + 1048576); // 8 KB

    prep_kernel<<<2560, 256, 0, stream>>>(x, Wexp, bexp, xb, Ws, bs);
    dim3 grid(NN / 128, MB / 128);  // (16, 256) — n fastest
    gemm_kernel<<<grid, 256, 0, stream>>>(xb, Ws, bs, out);
}